// Round 2
// baseline (430.410 us; speedup 1.0000x reference)
//
#include <hip/hip_runtime.h>
#include <hip/hip_bf16.h>
#include <stdint.h>

// Problem constants (fixed by the reference)
#define B_    4
#define N_    2048
#define DIM_  1024
#define H_    8
#define HD_   128
#define MTOK  (B_ * N_)          // 8192 tokens
#define SCALE_  0.08838834764831845f   // HD^-0.5
#define LOG2E_  1.4426950408889634f
#define QSCALE_ (SCALE_ * LOG2E_)      // folded into Q projection epilogue

typedef unsigned short u16;
typedef __attribute__((ext_vector_type(4))) float f32x4;
typedef __attribute__((ext_vector_type(8))) short s16x8;   // 8 bf16 (4 VGPRs) — MFMA A/B frag
typedef __attribute__((ext_vector_type(8))) u16  u16x8;
typedef __attribute__((ext_vector_type(4))) u16  u16x4;

__device__ __forceinline__ u16 f2bf(float f) {
    uint32_t i = __builtin_bit_cast(uint32_t, f);
    return (u16)((i + 0x7FFFu + ((i >> 16) & 1u)) >> 16);   // RNE
}

// direct global->LDS, 16B per lane; LDS dest = wave-uniform base + lane*16
__device__ __forceinline__ void gl_lds16(const u16* g, u16* l) {
    __builtin_amdgcn_global_load_lds((const __attribute__((address_space(1))) void*)g,
                                     (__attribute__((address_space(3))) void*)l,
                                     16, 0, 0);
}

// ---------------------------------------------------------------- cvt f32->bf16 (weights only)
__global__ __launch_bounds__(256) void cvt_f32_bf16(const float* __restrict__ src,
                                                    u16* __restrict__ dst, int n) {
    int i = (blockIdx.x * 256 + threadIdx.x) * 4;
    int stride = gridDim.x * 256 * 4;
    for (; i < n; i += stride) {
        float4 v = *(const float4*)(src + i);
        u16x4 o;
        o.x = f2bf(v.x); o.y = f2bf(v.y); o.z = f2bf(v.z); o.w = f2bf(v.w);
        *(u16x4*)(dst + i) = o;
    }
}

// ---------------------------------------------------------------- GEMM C = A @ Bt^T
// A [M,K] row-major: f32 (AF32=true, converted during staging) or bf16 (AF32=false,
//   staged via global_load_lds with pre-swizzled source).
// Bt [NN,K] bf16 row-major (torch Linear weight layout), global_load_lds staged.
// MODE 0: C -> bf16 head-split [B,H,N,HD] * scale   (Q, K projections)
// MODE 1: C -> bf16 transposed [B,H,HD,N] * scale   (V projection)
// MODE 2: C -> f32 row-major [M,NN] + bias          (output projection)
template <int MODE, bool AF32>
__global__ __launch_bounds__(256) void gemm_bt(const void* __restrict__ Ain,
                                               const u16* __restrict__ Bt,
                                               void* __restrict__ Cout,
                                               const float* __restrict__ bias,
                                               float scale, int M, int NN, int K) {
    __shared__ __align__(16) u16 lga[128 * 64];
    __shared__ __align__(16) u16 lgb[128 * 64];
    const int tid  = threadIdx.x;
    const int lane = tid & 63, wave = tid >> 6;
    const int wm = wave >> 1, wn = wave & 1;
    const int row0 = blockIdx.y * 128, col0 = blockIdx.x * 128;
    const float* Af = (const float*)Ain;
    const u16*  Ab  = (const u16*)Ain;

    f32x4 acc[4][4] = {};
    float4 ra[8];

    // A f32 path: 4 pair-chunks/thread (2 float4 each), swizzle constant per thread
    auto issueA = [&](int k0) {
        #pragma unroll
        for (int i = 0; i < 4; i++) {
            int p = tid + i * 256, r = p >> 3, pc = p & 7;
            const float* src = Af + (size_t)(row0 + r) * K + k0 + pc * 8;
            ra[2*i]   = *(const float4*)(src);
            ra[2*i+1] = *(const float4*)(src + 4);
        }
    };
    auto writeA = [&]() {
        #pragma unroll
        for (int i = 0; i < 4; i++) {
            int p = tid + i * 256, r = p >> 3, pc = p & 7;
            int sc = pc ^ (r & 7);
            float4 a = ra[2*i], b2 = ra[2*i+1];
            u16x8 o;
            o[0]=f2bf(a.x); o[1]=f2bf(a.y); o[2]=f2bf(a.z); o[3]=f2bf(a.w);
            o[4]=f2bf(b2.x); o[5]=f2bf(b2.y); o[6]=f2bf(b2.z); o[7]=f2bf(b2.w);
            *(u16x8*)(&lga[r * 64 + sc * 8]) = o;
        }
    };
    // bf16 global->LDS: linear LDS dest, XOR-swizzle applied on the GLOBAL source
    // (lane l of instr i covers row rb+(l>>3), fetches chunk (l&7)^(l>>3); rb%8==0)
    auto stageLds = [&](const u16* G, u16* L, int rowbase, int k0) {
        #pragma unroll
        for (int i = 0; i < 4; i++) {
            int rb = wave * 32 + i * 8;
            int r  = rb + (lane >> 3);
            int cc = (lane & 7) ^ (lane >> 3);
            gl_lds16(G + (size_t)(rowbase + r) * K + k0 + cc * 8, L + rb * 64);
        }
    };

    if (AF32) { issueA(0); writeA(); }
    else      stageLds(Ab, lga, row0, 0);
    stageLds(Bt, lgb, col0, 0);
    __syncthreads();

    const int NT = K / 64;
    for (int t = 0; t < NT; t++) {
        const bool has_next = (t + 1) < NT;
        if (AF32 && has_next) issueA((t + 1) * 64);   // prefetch next A tile into regs
        #pragma unroll
        for (int kk = 0; kk < 2; kk++) {
            s16x8 af[4], bfr[4];
            #pragma unroll
            for (int mi = 0; mi < 4; mi++) {
                int r = wm * 64 + mi * 16 + (lane & 15);
                int sc = (kk * 4 + (lane >> 4)) ^ (lane & 7);
                af[mi] = *(const s16x8*)(&lga[r * 64 + sc * 8]);
            }
            #pragma unroll
            for (int ni = 0; ni < 4; ni++) {
                int r = wn * 64 + ni * 16 + (lane & 15);
                int sc = (kk * 4 + (lane >> 4)) ^ (lane & 7);
                bfr[ni] = *(const s16x8*)(&lgb[r * 64 + sc * 8]);
            }
            #pragma unroll
            for (int mi = 0; mi < 4; mi++)
                #pragma unroll
                for (int ni = 0; ni < 4; ni++)
                    acc[mi][ni] = __builtin_amdgcn_mfma_f32_16x16x32_bf16(
                        af[mi], bfr[ni], acc[mi][ni], 0, 0, 0);
        }
        __syncthreads();
        if (has_next) {
            int k0 = (t + 1) * 64;
            if (AF32) writeA(); else stageLds(Ab, lga, row0, k0);
            stageLds(Bt, lgb, col0, k0);
            __syncthreads();
        }
    }

    // epilogue: D mapping col=lane&15, row=(lane>>4)*4+reg
    #pragma unroll
    for (int mi = 0; mi < 4; mi++) {
        #pragma unroll
        for (int ni = 0; ni < 4; ni++) {
            #pragma unroll
            for (int r = 0; r < 4; r++) {
                int grow = row0 + wm * 64 + mi * 16 + ((lane >> 4) << 2) + r;
                int gcol = col0 + wn * 64 + ni * 16 + (lane & 15);
                float vv = acc[mi][ni][r];
                if (MODE == 2) {
                    ((float*)Cout)[(size_t)grow * NN + gcol] = vv + bias[gcol];
                } else {
                    vv *= scale;
                    int bb = grow >> 11, n = grow & (N_ - 1);
                    int hh = gcol >> 7,  d = gcol & (HD_ - 1);
                    size_t idx = (MODE == 0)
                        ? ((size_t)(bb * H_ + hh) * N_ + n) * HD_ + d
                        : ((size_t)(bb * H_ + hh) * HD_ + d) * N_ + n;
                    ((u16*)Cout)[idx] = f2bf(vv);
                }
            }
        }
    }
}

// ---------------------------------------------------------------- gated flash attention
// Qh (pre-scaled by SCALE*log2e), Kh: [B,H,N,HD] bf16 ; Vt: [B,H,HD,N] bf16
// trans: [B,N,N] f32 ; out: x [B,N,DIM] bf16. Softmax tracked in log2 domain.
__global__ __launch_bounds__(512, 4) void attn_kernel(const u16* __restrict__ Qh,
                                                      const u16* __restrict__ Kh,
                                                      const u16* __restrict__ Vt,
                                                      const float* __restrict__ trans,
                                                      u16* __restrict__ xout) {
    __shared__ __align__(16) u16 kt[64 * 128];     // K tile [kv=64][d=128], swizzled
    __shared__ __align__(16) u16 vt[128 * 64];     // Vt tile [d=128][kv=64], swizzled
    __shared__ __align__(16) u16 plds[8][16 * 72]; // per-wave P buffer, padded stride 72

    const int tid = threadIdx.x, lane = tid & 63, wave = tid >> 6;
    const int qt = blockIdx.x, h = blockIdx.y, b = blockIdx.z;
    const int qrow_base = qt * 128 + wave * 16;

    const u16* Qbh = Qh + (size_t)(b * H_ + h) * N_ * HD_;
    const u16* Kbh = Kh + (size_t)(b * H_ + h) * N_ * HD_;
    const u16* Vbh = Vt + (size_t)(b * H_ + h) * HD_ * N_;
    // per-thread trans base: rows handled by this thread start here
    const float* trow = trans + (size_t)b * N_ * N_
                      + (size_t)(qrow_base + ((lane >> 4) << 2)) * N_ + (lane & 15);

    // Q fragments for this wave's 16 rows (kept in registers all kernel)
    s16x8 qf[4];
    {
        int r = qrow_base + (lane & 15);
        #pragma unroll
        for (int kd = 0; kd < 4; kd++)
            qf[kd] = *(const s16x8*)(Qbh + (size_t)r * HD_ + kd * 32 + ((lane >> 4) << 3));
    }

    float m[4], l[4];
    #pragma unroll
    for (int r = 0; r < 4; r++) { m[r] = -3.0e38f; l[r] = 0.f; }
    f32x4 ao[8] = {};

    // T14 async-stage: next-tile K/V held in regs while current tile computes
    u16x8 kreg[2], vreg[2];
    auto issueKV = [&](int kv0) {
        #pragma unroll
        for (int i = 0; i < 2; i++) {
            int c = tid + i * 512;
            kreg[i] = *(const u16x8*)(Kbh + (size_t)(kv0 + (c >> 4)) * HD_ + (c & 15) * 8);
            vreg[i] = *(const u16x8*)(Vbh + (size_t)(c >> 3) * N_ + kv0 + (c & 7) * 8);
        }
    };
    auto writeKV = [&]() {
        #pragma unroll
        for (int i = 0; i < 2; i++) {
            int c = tid + i * 512;
            { int r = c >> 4, cc = c & 15, sc = cc ^ (r & 15);
              *(u16x8*)(&kt[r * 128 + sc * 8]) = kreg[i]; }
            { int r = c >> 3, cc = c & 7,  sc = cc ^ (r & 7);
              *(u16x8*)(&vt[r * 64 + sc * 8]) = vreg[i]; }
        }
    };

    issueKV(0); writeKV(); __syncthreads();

    for (int kv0 = 0; kv0 < N_; kv0 += 64) {
        const bool has_next = (kv0 + 64) < N_;
        if (has_next) issueKV(kv0 + 64);   // HBM latency hides under S+softmax+PV

        // S = Qs @ K^T : 16 rows x 64 kv per wave (already includes SCALE*log2e)
        f32x4 s[4] = {};
        #pragma unroll
        for (int kd = 0; kd < 4; kd++)
            #pragma unroll
            for (int ni = 0; ni < 4; ni++) {
                int r = ni * 16 + (lane & 15);
                int sc = (kd * 4 + (lane >> 4)) ^ (lane & 15);
                s16x8 bfr = *(const s16x8*)(&kt[r * 128 + sc * 8]);
                s[ni] = __builtin_amdgcn_mfma_f32_16x16x32_bf16(qf[kd], bfr, s[ni], 0, 0, 0);
            }

        // gate (1 mul), track row max; s[] overwritten with gated values
        float pmax[4] = {-3.0e38f, -3.0e38f, -3.0e38f, -3.0e38f};
        #pragma unroll
        for (int ni = 0; ni < 4; ni++)
            #pragma unroll
            for (int r = 0; r < 4; r++) {
                float tt = trow[(size_t)r * N_ + kv0 + ni * 16];
                float gg = s[ni][r] * tt;
                s[ni][r] = gg;
                pmax[r] = fmaxf(pmax[r], gg);
            }
        #pragma unroll
        for (int r = 0; r < 4; r++) {
            float p = pmax[r];
            p = fmaxf(p, __shfl_xor(p, 1));
            p = fmaxf(p, __shfl_xor(p, 2));
            p = fmaxf(p, __shfl_xor(p, 4));
            p = fmaxf(p, __shfl_xor(p, 8));
            pmax[r] = p;
        }
        // T13 defer-rescale: skip O/l rescale while max grows < 8 (log2 units)
        bool need = false;
        #pragma unroll
        for (int r = 0; r < 4; r++) need = need || (pmax[r] > m[r] + 8.0f);
        if (__any(need)) {
            #pragma unroll
            for (int r = 0; r < 4; r++) {
                float mn = fmaxf(m[r], pmax[r]);
                float sfv = __builtin_amdgcn_exp2f(m[r] - mn);
                m[r] = mn;
                l[r] *= sfv;
                #pragma unroll
                for (int t = 0; t < 8; t++) ao[t][r] *= sfv;
            }
        }
        // P (exp2): denominator includes ALL entries; PV contribution zeroed where gated==0
        float rowsum[4] = {0.f, 0.f, 0.f, 0.f};
        u16* pw = &plds[wave][0];
        #pragma unroll
        for (int ni = 0; ni < 4; ni++)
            #pragma unroll
            for (int r = 0; r < 4; r++) {
                float gg = s[ni][r];
                float e = __builtin_amdgcn_exp2f(gg - m[r]);
                rowsum[r] += e;
                float pe = (gg != 0.0f) ? e : 0.0f;
                pw[(((lane >> 4) << 2) + r) * 72 + ni * 16 + (lane & 15)] = f2bf(pe);
            }
        #pragma unroll
        for (int r = 0; r < 4; r++) {
            float ssum = rowsum[r];
            ssum += __shfl_xor(ssum, 1);
            ssum += __shfl_xor(ssum, 2);
            ssum += __shfl_xor(ssum, 4);
            ssum += __shfl_xor(ssum, 8);
            l[r] += ssum;
        }
        // O += P @ V   (wave-local P round trip through LDS; in-order ds ops)
        #pragma unroll
        for (int kk = 0; kk < 2; kk++) {
            s16x8 pa = *(const s16x8*)(&pw[(lane & 15) * 72 + kk * 32 + ((lane >> 4) << 3)]);
            #pragma unroll
            for (int t = 0; t < 8; t++) {
                int r = t * 16 + (lane & 15);
                int sc = (kk * 4 + (lane >> 4)) ^ (lane & 7);
                s16x8 vb = *(const s16x8*)(&vt[r * 64 + sc * 8]);
                ao[t] = __builtin_amdgcn_mfma_f32_16x16x32_bf16(pa, vb, ao[t], 0, 0, 0);
            }
        }
        __syncthreads();                        // everyone done reading kt/vt
        if (has_next) { writeKV(); __syncthreads(); }
    }

    // normalize and write x[b, n, h*HD + d] (bf16)
    #pragma unroll
    for (int r = 0; r < 4; r++) {
        float inv = 1.0f / l[r];
        int n = qrow_base + ((lane >> 4) << 2) + r;
        u16* orow = xout + ((size_t)(b * N_ + n)) * DIM_ + h * HD_;
        #pragma unroll
        for (int t = 0; t < 8; t++)
            orow[t * 16 + (lane & 15)] = f2bf(ao[t][r] * inv);
    }
}

// ---------------------------------------------------------------- launch
extern "C" void kernel_launch(void* const* d_in, const int* in_sizes, int n_in,
                              void* d_out, int out_size, void* d_ws, size_t ws_size,
                              hipStream_t stream) {
    const float* q     = (const float*)d_in[0];
    const float* k     = (const float*)d_in[1];
    const float* v     = (const float*)d_in[2];
    const float* trans = (const float*)d_in[3];
    const float* Wq    = (const float*)d_in[4];
    const float* Wk    = (const float*)d_in[5];
    const float* Wv    = (const float*)d_in[6];
    const float* Wp    = (const float*)d_in[7];
    const float* bp    = (const float*)d_in[8];

    // workspace layout (72 MiB):
    //  [0,16M): xb attention output bf16
    //  [16M..24M): Wq,Wk,Wv,Wp bf16 (2 MiB each)
    //  [24M..40M): Qh   [40M..56M): Kh   [56M..72M): Vt
    char* ws = (char*)d_ws;
    u16* xb  = (u16*)(ws);
    u16* wqb = (u16*)(ws + (16u << 20));
    u16* wkb = (u16*)(ws + (18u << 20));
    u16* wvb = (u16*)(ws + (20u << 20));
    u16* wpb = (u16*)(ws + (22u << 20));
    u16* QhB = (u16*)(ws + (24u << 20));
    u16* KhB = (u16*)(ws + (40u << 20));
    u16* VtB = (u16*)(ws + (56u << 20));

    dim3 blk(256);
    cvt_f32_bf16<<<dim3(1024), blk, 0, stream>>>(Wq, wqb, DIM_ * DIM_);
    cvt_f32_bf16<<<dim3(1024), blk, 0, stream>>>(Wk, wkb, DIM_ * DIM_);
    cvt_f32_bf16<<<dim3(1024), blk, 0, stream>>>(Wv, wvb, DIM_ * DIM_);
    cvt_f32_bf16<<<dim3(1024), blk, 0, stream>>>(Wp, wpb, DIM_ * DIM_);

    dim3 pg(DIM_ / 128, MTOK / 128);   // (8, 64)

    gemm_bt<0, true><<<pg, blk, 0, stream>>>(q, wqb, QhB, nullptr, QSCALE_, MTOK, DIM_, DIM_);
    gemm_bt<0, true><<<pg, blk, 0, stream>>>(k, wkb, KhB, nullptr, 1.0f, MTOK, DIM_, DIM_);
    gemm_bt<1, true><<<pg, blk, 0, stream>>>(v, wvb, VtB, nullptr, 1.0f, MTOK, DIM_, DIM_);

    attn_kernel<<<dim3(N_ / 128, H_, B_), dim3(512), 0, stream>>>(QhB, KhB, VtB, trans, xb);

    gemm_bt<2, false><<<pg, blk, 0, stream>>>(xb, wpb, d_out, bp, 1.0f, MTOK, DIM_, DIM_);
}

// Round 3
// 289.849 us; speedup vs baseline: 1.4849x; 1.4849x over previous
//
#include <hip/hip_runtime.h>
#include <hip/hip_bf16.h>
#include <stdint.h>

// Problem constants (fixed by the reference)
#define B_    4
#define N_    2048
#define DIM_  1024
#define H_    8
#define HD_   128
#define MTOK  (B_ * N_)          // 8192 tokens
#define SCALE_  0.08838834764831845f   // HD^-0.5
#define LOG2E_  1.4426950408889634f
#define QSCALE_ (SCALE_ * LOG2E_)      // folded into Q projection epilogue

typedef unsigned short u16;
typedef __attribute__((ext_vector_type(4))) float f32x4;
typedef __attribute__((ext_vector_type(8))) short s16x8;   // 8 bf16 (4 VGPRs) — MFMA A/B frag
typedef __attribute__((ext_vector_type(8))) u16  u16x8;
typedef __attribute__((ext_vector_type(4))) u16  u16x4;

__device__ __forceinline__ u16 f2bf(float f) {
    uint32_t i = __builtin_bit_cast(uint32_t, f);
    return (u16)((i + 0x7FFFu + ((i >> 16) & 1u)) >> 16);   // RNE
}

// direct global->LDS, 16B per lane; LDS dest = wave-uniform base + lane*16
__device__ __forceinline__ void gl_lds16(const u16* g, u16* l) {
    __builtin_amdgcn_global_load_lds((const __attribute__((address_space(1))) void*)g,
                                     (__attribute__((address_space(3))) void*)l,
                                     16, 0, 0);
}

// ---------------------------------------------------------------- cvt f32->bf16
__global__ __launch_bounds__(256) void cvt_f32_bf16(const float* __restrict__ src,
                                                    u16* __restrict__ dst, int n) {
    int i = (blockIdx.x * 256 + threadIdx.x) * 4;
    int stride = gridDim.x * 256 * 4;
    for (; i < n; i += stride) {
        float4 v = *(const float4*)(src + i);
        u16x4 o;
        o.x = f2bf(v.x); o.y = f2bf(v.y); o.z = f2bf(v.z); o.w = f2bf(v.w);
        *(u16x4*)(dst + i) = o;
    }
}

// ---------------------------------------------------------------- GEMM C = A @ Bt^T
// A [M,K] bf16 row-major; Bt [NN,K] bf16 row-major (torch Linear weight layout).
// Both staged via global_load_lds (linear LDS dest, XOR-swizzle on global source).
// MODE 0: C -> bf16 head-split [B,H,N,HD] * scale   (Q, K projections)
// MODE 1: C -> bf16 transposed [B,H,HD,N] * scale   (V projection)
// MODE 2: C -> f32 row-major [M,NN] + bias          (output projection)
template <int MODE>
__global__ __launch_bounds__(256) void gemm_bt(const u16* __restrict__ A,
                                               const u16* __restrict__ Bt,
                                               void* __restrict__ Cout,
                                               const float* __restrict__ bias,
                                               float scale, int M, int NN, int K) {
    __shared__ __align__(16) u16 lga[128 * 64];
    __shared__ __align__(16) u16 lgb[128 * 64];
    const int tid  = threadIdx.x;
    const int lane = tid & 63, wave = tid >> 6;
    const int wm = wave >> 1, wn = wave & 1;
    const int row0 = blockIdx.y * 128, col0 = blockIdx.x * 128;

    f32x4 acc[4][4] = {};

    // wave w stages rows 32w..32w+31 of each 128x64 tile; lane l of instr i:
    // row rb+(l>>3), LDS slot (l&7), global chunk (l&7)^(l>>3)  [slot p holds chunk p^(r&7)]
    auto stageLds = [&](const u16* G, u16* L, int rowbase, int k0) {
        #pragma unroll
        for (int i = 0; i < 4; i++) {
            int rb = wave * 32 + i * 8;
            int r  = rb + (lane >> 3);
            int cc = (lane & 7) ^ (lane >> 3);
            gl_lds16(G + (size_t)(rowbase + r) * K + k0 + cc * 8, L + rb * 64);
        }
    };

    for (int k0 = 0; k0 < K; k0 += 64) {
        stageLds(A,  lga, row0, k0);
        stageLds(Bt, lgb, col0, k0);
        __syncthreads();   // drains vmcnt (gl_lds) before reads
        #pragma unroll
        for (int kk = 0; kk < 2; kk++) {
            s16x8 af[4], bfr[4];
            #pragma unroll
            for (int mi = 0; mi < 4; mi++) {
                int r = wm * 64 + mi * 16 + (lane & 15);
                int sc = (kk * 4 + (lane >> 4)) ^ (lane & 7);
                af[mi] = *(const s16x8*)(&lga[r * 64 + sc * 8]);
            }
            #pragma unroll
            for (int ni = 0; ni < 4; ni++) {
                int r = wn * 64 + ni * 16 + (lane & 15);
                int sc = (kk * 4 + (lane >> 4)) ^ (lane & 7);
                bfr[ni] = *(const s16x8*)(&lgb[r * 64 + sc * 8]);
            }
            #pragma unroll
            for (int mi = 0; mi < 4; mi++)
                #pragma unroll
                for (int ni = 0; ni < 4; ni++)
                    acc[mi][ni] = __builtin_amdgcn_mfma_f32_16x16x32_bf16(
                        af[mi], bfr[ni], acc[mi][ni], 0, 0, 0);
        }
        __syncthreads();
    }

    // epilogue: D mapping col=lane&15, row=(lane>>4)*4+reg
    #pragma unroll
    for (int mi = 0; mi < 4; mi++) {
        #pragma unroll
        for (int ni = 0; ni < 4; ni++) {
            #pragma unroll
            for (int r = 0; r < 4; r++) {
                int grow = row0 + wm * 64 + mi * 16 + ((lane >> 4) << 2) + r;
                int gcol = col0 + wn * 64 + ni * 16 + (lane & 15);
                float vv = acc[mi][ni][r];
                if (MODE == 2) {
                    ((float*)Cout)[(size_t)grow * NN + gcol] = vv + bias[gcol];
                } else {
                    vv *= scale;
                    int bb = grow >> 11, n = grow & (N_ - 1);
                    int hh = gcol >> 7,  d = gcol & (HD_ - 1);
                    size_t idx = (MODE == 0)
                        ? ((size_t)(bb * H_ + hh) * N_ + n) * HD_ + d
                        : ((size_t)(bb * H_ + hh) * HD_ + d) * N_ + n;
                    ((u16*)Cout)[idx] = f2bf(vv);
                }
            }
        }
    }
}

// ---------------------------------------------------------------- gated flash attention
// Qh (pre-scaled by SCALE*log2e), Kh: [B,H,N,HD] bf16 ; Vt: [B,H,HD,N] bf16
// trans: [B,N,N] f32 ; out: x [B,N,DIM] bf16. Softmax tracked in log2 domain.
__global__ __launch_bounds__(512) void attn_kernel(const u16* __restrict__ Qh,
                                                   const u16* __restrict__ Kh,
                                                   const u16* __restrict__ Vt,
                                                   const float* __restrict__ trans,
                                                   u16* __restrict__ xout) {
    __shared__ __align__(16) u16 kt[64 * 128];     // K tile [kv=64][d=128], swizzle ^(r&15)
    __shared__ __align__(16) u16 vt[128 * 64];     // Vt tile [d=128][kv=64], swizzle ^(r&7)
    __shared__ __align__(16) u16 plds[8][16 * 72]; // per-wave P buffer, padded stride 72

    const int tid = threadIdx.x, lane = tid & 63, wave = tid >> 6;
    const int qt = blockIdx.x, h = blockIdx.y, b = blockIdx.z;
    const int qrow_base = qt * 128 + wave * 16;

    const u16* Qbh = Qh + (size_t)(b * H_ + h) * N_ * HD_;
    const u16* Kbh = Kh + (size_t)(b * H_ + h) * N_ * HD_;
    const u16* Vbh = Vt + (size_t)(b * H_ + h) * HD_ * N_;
    const float* trow = trans + (size_t)b * N_ * N_
                      + (size_t)(qrow_base + ((lane >> 4) << 2)) * N_ + (lane & 15);

    // Q fragments for this wave's 16 rows (kept in registers all kernel)
    s16x8 qf[4];
    {
        int r = qrow_base + (lane & 15);
        #pragma unroll
        for (int kd = 0; kd < 4; kd++)
            qf[kd] = *(const s16x8*)(Qbh + (size_t)r * HD_ + kd * 32 + ((lane >> 4) << 3));
    }

    // K/V tile staging via global_load_lds (linear LDS dest, pre-swizzled source).
    // kt: wave w stages rows 8w..8w+7 (16 slots/row); vt: rows 16w..16w+15 (8 slots/row).
    auto stageKV = [&](int kv0) {
        int rbk = wave * 8, rbv = wave * 16;
        #pragma unroll
        for (int j = 0; j < 2; j++) {
            int c = j * 64 + lane;
            int rk = rbk + (c >> 4);
            int ck = (c & 15) ^ (rk & 15);
            gl_lds16(Kbh + (size_t)(kv0 + rk) * HD_ + ck * 8, kt + rbk * 128 + j * 512);
            int rv = rbv + (c >> 3);
            int cv = (c & 7) ^ (rv & 7);
            gl_lds16(Vbh + (size_t)rv * N_ + kv0 + cv * 8, vt + rbv * 64 + j * 512);
        }
    };

    float m[4], l[4];
    #pragma unroll
    for (int r = 0; r < 4; r++) { m[r] = -3.0e38f; l[r] = 0.f; }
    f32x4 ao[8] = {};

    for (int kv0 = 0; kv0 < N_; kv0 += 64) {
        stageKV(kv0);
        __syncthreads();   // drains vmcnt before LDS reads

        // S = Qs @ K^T : 16 rows x 64 kv per wave (Q pre-includes SCALE*log2e)
        f32x4 s[4] = {};
        #pragma unroll
        for (int kd = 0; kd < 4; kd++)
            #pragma unroll
            for (int ni = 0; ni < 4; ni++) {
                int r = ni * 16 + (lane & 15);
                int sc = (kd * 4 + (lane >> 4)) ^ (lane & 15);
                s16x8 bfr = *(const s16x8*)(&kt[r * 128 + sc * 8]);
                s[ni] = __builtin_amdgcn_mfma_f32_16x16x32_bf16(qf[kd], bfr, s[ni], 0, 0, 0);
            }

        // gate (1 mul), track row max; s[] overwritten with gated values
        float pmax[4] = {-3.0e38f, -3.0e38f, -3.0e38f, -3.0e38f};
        #pragma unroll
        for (int ni = 0; ni < 4; ni++)
            #pragma unroll
            for (int r = 0; r < 4; r++) {
                float tt = trow[(size_t)r * N_ + kv0 + ni * 16];
                float gg = s[ni][r] * tt;
                s[ni][r] = gg;
                pmax[r] = fmaxf(pmax[r], gg);
            }
        #pragma unroll
        for (int r = 0; r < 4; r++) {
            float p = pmax[r];
            p = fmaxf(p, __shfl_xor(p, 1));
            p = fmaxf(p, __shfl_xor(p, 2));
            p = fmaxf(p, __shfl_xor(p, 4));
            p = fmaxf(p, __shfl_xor(p, 8));
            pmax[r] = p;
        }
        // defer-rescale (T13): skip O/l rescale while max growth < 8 (log2 units)
        bool need = false;
        #pragma unroll
        for (int r = 0; r < 4; r++) need = need || (pmax[r] > m[r] + 8.0f);
        if (__any(need)) {
            #pragma unroll
            for (int r = 0; r < 4; r++) {
                float mn = fmaxf(m[r], pmax[r]);
                float sfv = __builtin_amdgcn_exp2f(m[r] - mn);
                m[r] = mn;
                l[r] *= sfv;
                #pragma unroll
                for (int t = 0; t < 8; t++) ao[t][r] *= sfv;
            }
        }
        // P (exp2): denominator includes ALL entries; PV contribution zeroed where gated==0
        float rowsum[4] = {0.f, 0.f, 0.f, 0.f};
        u16* pw = &plds[wave][0];
        #pragma unroll
        for (int ni = 0; ni < 4; ni++)
            #pragma unroll
            for (int r = 0; r < 4; r++) {
                float gg = s[ni][r];
                float e = __builtin_amdgcn_exp2f(gg - m[r]);
                rowsum[r] += e;
                float pe = (gg != 0.0f) ? e : 0.0f;
                pw[(((lane >> 4) << 2) + r) * 72 + ni * 16 + (lane & 15)] = f2bf(pe);
            }
        #pragma unroll
        for (int r = 0; r < 4; r++) {
            float ssum = rowsum[r];
            ssum += __shfl_xor(ssum, 1);
            ssum += __shfl_xor(ssum, 2);
            ssum += __shfl_xor(ssum, 4);
            ssum += __shfl_xor(ssum, 8);
            l[r] += ssum;
        }
        // O += P @ V   (wave-local P round trip through LDS; in-order ds ops)
        #pragma unroll
        for (int kk = 0; kk < 2; kk++) {
            s16x8 pa = *(const s16x8*)(&pw[(lane & 15) * 72 + kk * 32 + ((lane >> 4) << 3)]);
            #pragma unroll
            for (int t = 0; t < 8; t++) {
                int r = t * 16 + (lane & 15);
                int sc = (kk * 4 + (lane >> 4)) ^ (lane & 7);
                s16x8 vb = *(const s16x8*)(&vt[r * 64 + sc * 8]);
                ao[t] = __builtin_amdgcn_mfma_f32_16x16x32_bf16(pa, vb, ao[t], 0, 0, 0);
            }
        }
        __syncthreads();   // everyone done reading kt/vt before next stage
    }

    // normalize and write x[b, n, h*HD + d] (bf16)
    #pragma unroll
    for (int r = 0; r < 4; r++) {
        float inv = 1.0f / l[r];
        int n = qrow_base + ((lane >> 4) << 2) + r;
        u16* orow = xout + ((size_t)(b * N_ + n)) * DIM_ + h * HD_;
        #pragma unroll
        for (int t = 0; t < 8; t++)
            orow[t * 16 + (lane & 15)] = f2bf(ao[t][r] * inv);
    }
}

// ---------------------------------------------------------------- launch
extern "C" void kernel_launch(void* const* d_in, const int* in_sizes, int n_in,
                              void* d_out, int out_size, void* d_ws, size_t ws_size,
                              hipStream_t stream) {
    const float* q     = (const float*)d_in[0];
    const float* k     = (const float*)d_in[1];
    const float* v     = (const float*)d_in[2];
    const float* trans = (const float*)d_in[3];
    const float* Wq    = (const float*)d_in[4];
    const float* Wk    = (const float*)d_in[5];
    const float* Wv    = (const float*)d_in[6];
    const float* Wp    = (const float*)d_in[7];
    const float* bp    = (const float*)d_in[8];

    // workspace layout (72 MiB total):
    //  [0,16M): tmp bf16 input staging (q/k/v serially), later reused as attention out x
    //  [16M..24M): Wq,Wk,Wv,Wp bf16 (2 MiB each)
    //  [24M..40M): Qh   [40M..56M): Kh   [56M..72M): Vt
    char* ws = (char*)d_ws;
    u16* tmp = (u16*)(ws);
    u16* wqb = (u16*)(ws + (16u << 20));
    u16* wkb = (u16*)(ws + (18u << 20));
    u16* wvb = (u16*)(ws + (20u << 20));
    u16* wpb = (u16*)(ws + (22u << 20));
    u16* QhB = (u16*)(ws + (24u << 20));
    u16* KhB = (u16*)(ws + (40u << 20));
    u16* VtB = (u16*)(ws + (56u << 20));
    u16* xb  = tmp;   // reuse after V projection is done

    dim3 blk(256);
    cvt_f32_bf16<<<dim3(1024), blk, 0, stream>>>(Wq, wqb, DIM_ * DIM_);
    cvt_f32_bf16<<<dim3(1024), blk, 0, stream>>>(Wk, wkb, DIM_ * DIM_);
    cvt_f32_bf16<<<dim3(1024), blk, 0, stream>>>(Wv, wvb, DIM_ * DIM_);
    cvt_f32_bf16<<<dim3(1024), blk, 0, stream>>>(Wp, wpb, DIM_ * DIM_);

    dim3 pg(DIM_ / 128, MTOK / 128);   // (8, 64)

    cvt_f32_bf16<<<dim3(8192), blk, 0, stream>>>(q, tmp, MTOK * DIM_);
    gemm_bt<0><<<pg, blk, 0, stream>>>(tmp, wqb, QhB, nullptr, QSCALE_, MTOK, DIM_, DIM_);
    cvt_f32_bf16<<<dim3(8192), blk, 0, stream>>>(k, tmp, MTOK * DIM_);
    gemm_bt<0><<<pg, blk, 0, stream>>>(tmp, wkb, KhB, nullptr, 1.0f, MTOK, DIM_, DIM_);
    cvt_f32_bf16<<<dim3(8192), blk, 0, stream>>>(v, tmp, MTOK * DIM_);
    gemm_bt<1><<<pg, blk, 0, stream>>>(tmp, wvb, VtB, nullptr, 1.0f, MTOK, DIM_, DIM_);

    attn_kernel<<<dim3(N_ / 128, H_, B_), dim3(512), 0, stream>>>(QhB, KhB, VtB, trans, xb);

    gemm_bt<2><<<pg, blk, 0, stream>>>(xb, wpb, d_out, bp, 1.0f, MTOK, DIM_, DIM_);
}